// Round 3
// baseline (145.561 us; speedup 1.0000x reference)
//
#include <hip/hip_runtime.h>

// Householder reflection per row: out = z - 2 * v * (v.z) / (v.v)
// B = 1048576 rows, L = 64 fp32 per row.
//
// Layout: 16 lanes per row (one float4 each), 4 rows batched per thread.
// Each wave owns 16 consecutive rows; load instruction j covers rows
// 4j..4j+3 = 1 KiB fully contiguous. 8 loads issued up front (high MLP),
// then 8 independent 4-step __shfl_xor reduction chains (4 rows x {v.z, v.v})
// interleave to hide shuffle latency.
__global__ void __launch_bounds__(256) HF_28063316312693_kernel(
        const float* __restrict__ v,
        const float* __restrict__ z,
        float* __restrict__ out) {
    const int tid    = blockIdx.x * blockDim.x + threadIdx.x;
    const int wave   = tid >> 6;       // global wave id; owns rows [wave*16, wave*16+16)
    const int lane   = tid & 63;
    const int l4     = lane & 15;      // float4 slot within the row
    const int subrow = lane >> 4;      // 0..3

    // Row for batch j: wave*16 + 4*j + subrow. Batch j adds 4 rows = 256 floats.
    const size_t b0 = ((size_t)wave * 16 + subrow) * 64 + (size_t)l4 * 4;

    const float4 va = *reinterpret_cast<const float4*>(v + b0);
    const float4 vb = *reinterpret_cast<const float4*>(v + b0 + 256);
    const float4 vc = *reinterpret_cast<const float4*>(v + b0 + 512);
    const float4 vd = *reinterpret_cast<const float4*>(v + b0 + 768);
    const float4 za = *reinterpret_cast<const float4*>(z + b0);
    const float4 zb = *reinterpret_cast<const float4*>(z + b0 + 256);
    const float4 zc = *reinterpret_cast<const float4*>(z + b0 + 512);
    const float4 zd = *reinterpret_cast<const float4*>(z + b0 + 768);

    float vza = va.x * za.x + va.y * za.y + va.z * za.z + va.w * za.w;
    float nna = va.x * va.x + va.y * va.y + va.z * va.z + va.w * va.w;
    float vzb = vb.x * zb.x + vb.y * zb.y + vb.z * zb.z + vb.w * zb.w;
    float nnb = vb.x * vb.x + vb.y * vb.y + vb.z * vb.z + vb.w * vb.w;
    float vzc = vc.x * zc.x + vc.y * zc.y + vc.z * zc.z + vc.w * zc.w;
    float nnc = vc.x * vc.x + vc.y * vc.y + vc.z * vc.z + vc.w * vc.w;
    float vzd = vd.x * zd.x + vd.y * zd.y + vd.z * zd.z + vd.w * zd.w;
    float nnd = vd.x * vd.x + vd.y * vd.y + vd.z * vd.z + vd.w * vd.w;

    // 8 independent 4-step reductions across each aligned 16-lane group
    // (xor 1,2,4,8 stays within the group).
    #pragma unroll
    for (int off = 1; off < 16; off <<= 1) {
        vza += __shfl_xor(vza, off, 64);
        nna += __shfl_xor(nna, off, 64);
        vzb += __shfl_xor(vzb, off, 64);
        nnb += __shfl_xor(nnb, off, 64);
        vzc += __shfl_xor(vzc, off, 64);
        nnc += __shfl_xor(nnc, off, 64);
        vzd += __shfl_xor(vzd, off, 64);
        nnd += __shfl_xor(nnd, off, 64);
    }

    const float sa = -2.0f * vza / nna;
    const float sb = -2.0f * vzb / nnb;
    const float sc = -2.0f * vzc / nnc;
    const float sd = -2.0f * vzd / nnd;

    float4 oa, ob, oc, od;
    oa.x = fmaf(sa, va.x, za.x); oa.y = fmaf(sa, va.y, za.y);
    oa.z = fmaf(sa, va.z, za.z); oa.w = fmaf(sa, va.w, za.w);
    ob.x = fmaf(sb, vb.x, zb.x); ob.y = fmaf(sb, vb.y, zb.y);
    ob.z = fmaf(sb, vb.z, zb.z); ob.w = fmaf(sb, vb.w, zb.w);
    oc.x = fmaf(sc, vc.x, zc.x); oc.y = fmaf(sc, vc.y, zc.y);
    oc.z = fmaf(sc, vc.z, zc.z); oc.w = fmaf(sc, vc.w, zc.w);
    od.x = fmaf(sd, vd.x, zd.x); od.y = fmaf(sd, vd.y, zd.y);
    od.z = fmaf(sd, vd.z, zd.z); od.w = fmaf(sd, vd.w, zd.w);

    *reinterpret_cast<float4*>(out + b0)       = oa;
    *reinterpret_cast<float4*>(out + b0 + 256) = ob;
    *reinterpret_cast<float4*>(out + b0 + 512) = oc;
    *reinterpret_cast<float4*>(out + b0 + 768) = od;
}

extern "C" void kernel_launch(void* const* d_in, const int* in_sizes, int n_in,
                              void* d_out, int out_size, void* d_ws, size_t ws_size,
                              hipStream_t stream) {
    const float* v = (const float*)d_in[0];
    const float* z = (const float*)d_in[1];
    float* out = (float*)d_out;
    const int B = in_sizes[0] / 64;  // 1048576

    // 16 rows per wave, 4 waves per block -> 64 rows per block.
    const int block = 256;
    const int grid = B / 64;  // 16384 (B is a power of two, exact fit)

    HF_28063316312693_kernel<<<grid, block, 0, stream>>>(v, z, out);
}

// Round 5
// 117.067 us; speedup vs baseline: 1.2434x; 1.2434x over previous
//
#include <hip/hip_runtime.h>

// Householder reflection per row: out = z - 2 * v * (v.z) / (v.v)
// B = 1048576 rows, L = 64 fp32 per row.
//
// R3 structure (16 lanes/row, 4 rows per thread, 1 KiB contiguous wave loads)
// + cache hints: nontemporal store for out (never re-read -> don't allocate
// in L2/L3), nontemporal load for v (bias L3 retention toward z).
// Uses clang ext_vector_type since __builtin_nontemporal_* rejects the
// HIP_vector_type struct float4.
typedef float f32x4 __attribute__((ext_vector_type(4)));

__global__ void __launch_bounds__(256) HF_28063316312693_kernel(
        const float* __restrict__ v,
        const float* __restrict__ z,
        float* __restrict__ out) {
    const int tid    = blockIdx.x * blockDim.x + threadIdx.x;
    const int wave   = tid >> 6;       // owns rows [wave*16, wave*16+16)
    const int lane   = tid & 63;
    const int l4     = lane & 15;      // float4 slot within the row
    const int subrow = lane >> 4;      // 0..3

    const size_t b0 = ((size_t)wave * 16 + subrow) * 64 + (size_t)l4 * 4;

    const f32x4* vp = reinterpret_cast<const f32x4*>(v + b0);
    const f32x4* zp = reinterpret_cast<const f32x4*>(z + b0);

    const f32x4 va = __builtin_nontemporal_load(vp);
    const f32x4 vb = __builtin_nontemporal_load(vp + 64);   // +256 floats
    const f32x4 vc = __builtin_nontemporal_load(vp + 128);  // +512 floats
    const f32x4 vd = __builtin_nontemporal_load(vp + 192);  // +768 floats
    const f32x4 za = zp[0];
    const f32x4 zb = zp[64];
    const f32x4 zc = zp[128];
    const f32x4 zd = zp[192];

    float vza = va.x * za.x + va.y * za.y + va.z * za.z + va.w * za.w;
    float nna = va.x * va.x + va.y * va.y + va.z * va.z + va.w * va.w;
    float vzb = vb.x * zb.x + vb.y * zb.y + vb.z * zb.z + vb.w * zb.w;
    float nnb = vb.x * vb.x + vb.y * vb.y + vb.z * vb.z + vb.w * vb.w;
    float vzc = vc.x * zc.x + vc.y * zc.y + vc.z * zc.z + vc.w * zc.w;
    float nnc = vc.x * vc.x + vc.y * vc.y + vc.z * vc.z + vc.w * vc.w;
    float vzd = vd.x * zd.x + vd.y * zd.y + vd.z * zd.z + vd.w * zd.w;
    float nnd = vd.x * vd.x + vd.y * vd.y + vd.z * vd.z + vd.w * vd.w;

    #pragma unroll
    for (int off = 1; off < 16; off <<= 1) {
        vza += __shfl_xor(vza, off, 64);
        nna += __shfl_xor(nna, off, 64);
        vzb += __shfl_xor(vzb, off, 64);
        nnb += __shfl_xor(nnb, off, 64);
        vzc += __shfl_xor(vzc, off, 64);
        nnc += __shfl_xor(nnc, off, 64);
        vzd += __shfl_xor(vzd, off, 64);
        nnd += __shfl_xor(nnd, off, 64);
    }

    const float sa = -2.0f * vza / nna;
    const float sb = -2.0f * vzb / nnb;
    const float sc = -2.0f * vzc / nnc;
    const float sd = -2.0f * vzd / nnd;

    f32x4 oa, ob, oc, od;
    oa.x = fmaf(sa, va.x, za.x); oa.y = fmaf(sa, va.y, za.y);
    oa.z = fmaf(sa, va.z, za.z); oa.w = fmaf(sa, va.w, za.w);
    ob.x = fmaf(sb, vb.x, zb.x); ob.y = fmaf(sb, vb.y, zb.y);
    ob.z = fmaf(sb, vb.z, zb.z); ob.w = fmaf(sb, vb.w, zb.w);
    oc.x = fmaf(sc, vc.x, zc.x); oc.y = fmaf(sc, vc.y, zc.y);
    oc.z = fmaf(sc, vc.z, zc.z); oc.w = fmaf(sc, vc.w, zc.w);
    od.x = fmaf(sd, vd.x, zd.x); od.y = fmaf(sd, vd.y, zd.y);
    od.z = fmaf(sd, vd.z, zd.z); od.w = fmaf(sd, vd.w, zd.w);

    f32x4* op = reinterpret_cast<f32x4*>(out + b0);
    __builtin_nontemporal_store(oa, op);
    __builtin_nontemporal_store(ob, op + 64);
    __builtin_nontemporal_store(oc, op + 128);
    __builtin_nontemporal_store(od, op + 192);
}

extern "C" void kernel_launch(void* const* d_in, const int* in_sizes, int n_in,
                              void* d_out, int out_size, void* d_ws, size_t ws_size,
                              hipStream_t stream) {
    const float* v = (const float*)d_in[0];
    const float* z = (const float*)d_in[1];
    float* out = (float*)d_out;
    const int B = in_sizes[0] / 64;  // 1048576

    const int block = 256;
    const int grid = B / 64;  // 64 rows per block, exact fit

    HF_28063316312693_kernel<<<grid, block, 0, stream>>>(v, z, out);
}